// Round 5
// baseline (364.039 us; speedup 1.0000x reference)
//
#include <hip/hip_runtime.h>

// SparseCodebook: out[b] = min_k mean_d |codes[b,d] - centroids[cls[b],k,d]|
// B=262144, NUM_CLASSES=1000, K=4, D=256.
//
// R4 post-mortem: fp16 table (+L2 residency) gained only 15us -> gathers were
// already mostly cache-served. Remaining suspect: latency. One-shot waves stall
// on the pred->gather dependency chain every 4 samples.
// R5: persistent waves (2048 blocks = 32 waves/CU) with a 1-deep software
// pipeline: while computing group i, group i+1's cls + codes loads are already
// in flight. If this is neutral, the kernel is at the 43us codes-stream floor.

#define B_TOTAL     262144
#define NUM_CLASSES 1000
#define KC          4
#define DIM         256

#define NBLK        2048
#define WAVES_TOT   (NBLK * 256 / 64)        // 8192
#define P_TOTAL     (B_TOTAL / 4)            // 65536 sample-groups of 4
#define ITERS       (P_TOTAL / WAVES_TOT)    // 8, exact

typedef float    vf4 __attribute__((ext_vector_type(4)));
typedef _Float16 vh4 __attribute__((ext_vector_type(4)));

// centroids fp32 -> fp16 into ws (2 MB table, L2-resident).
__global__ __launch_bounds__(256) void convert_kernel(
    const float* __restrict__ cent_f32, _Float16* __restrict__ cent_f16)
{
    const int i = blockIdx.x * 256 + threadIdx.x;
    const int n = NUM_CLASSES * KC * DIM / 4;
    if (i < n) {
        const vf4 v = ((const vf4*)cent_f32)[i];
        vh4 h;
        h.x = (_Float16)v.x; h.y = (_Float16)v.y;
        h.z = (_Float16)v.z; h.w = (_Float16)v.w;
        ((vh4*)cent_f16)[i] = h;
    }
}

// Persistent: each wave handles ITERS groups of 4 samples; 16-lane quarter q
// owns sample 4p+q; lane covers dims [4*(j*16+l), +4), j=0..3.
__global__ __launch_bounds__(256) void sparse_codebook_pipe(
    const float*    __restrict__ codes,
    const int*      __restrict__ pred_class,
    const _Float16* __restrict__ cent_f16,
    float*          __restrict__ out)
{
    const int wave = (blockIdx.x * 256 + threadIdx.x) >> 6;
    const int lane = threadIdx.x & 63;
    const int q    = lane >> 4;
    const int l    = lane & 15;

    int p = wave;                                    // sample-group index

    // ---- prologue: issue loads for group 0 ----
    int cls_cur = pred_class[p * 4 + q];
    const vf4* crow = (const vf4*)codes + (size_t)(p * 4 + q) * 64;
    vf4 c_cur[4];
#pragma unroll
    for (int j = 0; j < 4; ++j)
        c_cur[j] = __builtin_nontemporal_load(&crow[j * 16 + l]);

    for (int it = 0; it < ITERS; ++it) {
        // ---- issue next group's loads before using current ----
        const int pn = p + WAVES_TOT;
        int cls_nxt = 0;
        vf4 c_nxt[4];
        if (it + 1 < ITERS) {
            cls_nxt = pred_class[pn * 4 + q];
            const vf4* nrow = (const vf4*)codes + (size_t)(pn * 4 + q) * 64;
#pragma unroll
            for (int j = 0; j < 4; ++j)
                c_nxt[j] = __builtin_nontemporal_load(&nrow[j * 16 + l]);
        }

        // ---- compute current group ----
        const vh4* cbase = (const vh4*)cent_f16 + (size_t)cls_cur * (KC * DIM / 4);
        float s[KC];
#pragma unroll
        for (int k = 0; k < KC; ++k) {
            float acc = 0.0f;
#pragma unroll
            for (int j = 0; j < 4; ++j) {
                const vh4 g = cbase[k * 64 + j * 16 + l];
                acc += fabsf(c_cur[0 + j].x - (float)g.x)
                     + fabsf(c_cur[0 + j].y - (float)g.y)
                     + fabsf(c_cur[0 + j].z - (float)g.z)
                     + fabsf(c_cur[0 + j].w - (float)g.w);
            }
            s[k] = acc;
        }

        // quarter-wave butterfly (xor masks 8,4,2,1 stay within the quarter)
#pragma unroll
        for (int off = 8; off >= 1; off >>= 1)
#pragma unroll
            for (int k = 0; k < KC; ++k)
                s[k] += __shfl_xor(s[k], off, 64);

        if (l == 0) {
            const float m = fminf(fminf(s[0], s[1]), fminf(s[2], s[3]));
            __builtin_nontemporal_store(m * (1.0f / (float)DIM), &out[p * 4 + q]);
        }

        // ---- rotate pipeline ----
        p = pn;
        cls_cur = cls_nxt;
#pragma unroll
        for (int j = 0; j < 4; ++j) c_cur[j] = c_nxt[j];
    }
}

extern "C" void kernel_launch(void* const* d_in, const int* in_sizes, int n_in,
                              void* d_out, int out_size, void* d_ws, size_t ws_size,
                              hipStream_t stream) {
    const float* codes = (const float*)d_in[0];
    const int*   pred  = (const int*)d_in[1];
    const float* cents = (const float*)d_in[2];
    float*       out   = (float*)d_out;
    _Float16*    tab   = (_Float16*)d_ws;

    const int nvec = NUM_CLASSES * KC * DIM / 4;
    convert_kernel<<<(nvec + 255) / 256, 256, 0, stream>>>(cents, tab);

    sparse_codebook_pipe<<<NBLK, 256, 0, stream>>>(codes, pred, tab, out);
}